// Round 11
// baseline (115.285 us; speedup 1.0000x reference)
//
#include <hip/hip_runtime.h>

// Problem constants (match reference): B=8192, P=32, D=128, V=100000
#define BB 8192
#define PP 32
#define DD 128

// Native 16B vector for __builtin_nontemporal_load (the builtin rejects
// HIP_vector_type; an ext_vector_type pointer compiles to the same
// global_load_dwordx4, with the nt bit set).
typedef float f4 __attribute__((ext_vector_type(4)));

// R9 skeleton + NON-TEMPORAL embed loads (single-variable experiment).
//
// Evidence so far: R7 (deep MLP), R8 (address-sorted), R9 (minimal
// line-lookups) are all neutral at ~20us = 1.7 TB/s effective gather.
// MLP/TLP/request-shaping are exhausted. Remaining suspect: L1 (TCP)
// line-ALLOCATION under 100% miss + zero reuse (256 KB touched per CU
// per pass through a 32 KB cache). NT loads skip L1 allocation / victim
// handling on the miss path.
//
// Everything else identical to R9: one wave per batch row, half-wave
// loads one full 512B row per instruction (8 lines/pair, minimal),
// 4 pair-loads batched in registers, stride-33 wave-private LDS
// reduction, no __syncthreads, no per-pair shuffle chains.
__global__ __launch_bounds__(256) void hs_loss_kernel(
    const float* __restrict__ hidden,      // [B, D]
    const int*   __restrict__ path,        // [B, P]
    const int*   __restrict__ path_len,    // [B]
    const int*   __restrict__ code,        // [B, P]
    const float* __restrict__ embed,       // [V, D]
    float2* __restrict__ partials)         // [BB] {loss_sum, len} per row
{
    const int tid = threadIdx.x;
    const int w   = tid >> 6;              // wave in block, 0..3
    const int l   = tid & 63;              // lane
    const int h   = l >> 5;                // half, 0 or 1
    const int hl  = l & 31;                // lane within half
    const int b   = blockIdx.x * 4 + w;    // this wave's batch row

    __shared__ float plds[4][PP * 33];     // 4 wave-private slices, 16.5 KB
    float* const myp = plds[w];

    const int len   = path_len[b];         // wave-uniform
    const int idx_l = path[b * PP + hl];   // lane hl holds pair hl's index
    const int cd_l  = code[b * PP + hl];   // (both halves duplicate)

    // lane's 16B slice of the hidden row (both halves identical)
    const float4 hv = ((const float4*)(hidden + (size_t)b * DD))[hl];

    // ---- phase 1: batched full-row NT loads + partial dots ----
    #pragma unroll
    for (int batch = 0; batch < 4; ++batch) {
        const int p0 = batch * 8;          // this batch covers pids p0..p0+7
        if (p0 < len) {                    // wave-uniform batch skip
            int pid[4];
            f4 e[4];
            #pragma unroll
            for (int j = 0; j < 4; ++j) {
                pid[j] = p0 + 2 * j + h;   // halves interleave pairs
                const int idx = __shfl(idx_l, pid[j]);
                if (pid[j] < len)          // half-uniform exec mask
                    e[j] = __builtin_nontemporal_load(
                        (const f4*)(embed + (size_t)idx * DD) + hl);
            }
            #pragma unroll
            for (int j = 0; j < 4; ++j) {
                if (pid[j] < len) {
                    const float pr = e[j].x * hv.x + e[j].y * hv.y
                                   + e[j].z * hv.z + e[j].w * hv.w;
                    myp[pid[j] * 33 + hl] = pr;
                }
            }
        }
    }

    // ---- phase 2: half-split partial-sum (same-wave LDS, no barrier) ----
    const int lp = l & 31;                 // pair this lane reduces
    const int kb = h * 16;                 // lanes 0-31: k 0..15; 32-63: 16..31
    float psum = 0.0f;
    #pragma unroll
    for (int k = 0; k < 16; ++k) psum += myp[lp * 33 + kb + k];
    const float dot = psum + __shfl_xor(psum, 32);

    // ---- phase 3: softplus + wave reduction ----
    float loss = 0.0f;
    if (l < 32 && lp < len) {
        // loss = softplus(code ? -dot : dot), stable BCE form
        const float z = cd_l ? -dot : dot;
        loss = fmaxf(z, 0.0f) + __logf(1.0f + __expf(-fabsf(z)));
    }
    #pragma unroll
    for (int m = 1; m <= 32; m <<= 1) loss += __shfl_xor(loss, m);
    if (l == 0) partials[b] = make_float2(loss, (float)len);
}

// Single-block reduction of the 8192 per-row partials + final divide.
__global__ __launch_bounds__(1024) void hs_finalize_kernel(
    const float2* __restrict__ partials, float* __restrict__ out)
{
    const int tid = threadIdx.x;
    float ls = 0.0f, cs = 0.0f;
    #pragma unroll
    for (int k = 0; k < BB / 1024; ++k) {
        const float2 v = partials[tid + k * 1024];
        ls += v.x;
        cs += v.y;
    }
    #pragma unroll
    for (int m = 1; m <= 32; m <<= 1) {
        ls += __shfl_xor(ls, m);
        cs += __shfl_xor(cs, m);
    }
    __shared__ float s_l[16], s_c[16];
    const int wave = tid >> 6;
    if ((tid & 63) == 0) { s_l[wave] = ls; s_c[wave] = cs; }
    __syncthreads();
    if (tid == 0) {
        float L = 0.0f, C = 0.0f;
        #pragma unroll
        for (int wv = 0; wv < 16; ++wv) { L += s_l[wv]; C += s_c[wv]; }
        out[0] = L / C;
    }
}

extern "C" void kernel_launch(void* const* d_in, const int* in_sizes, int n_in,
                              void* d_out, int out_size, void* d_ws, size_t ws_size,
                              hipStream_t stream) {
    const float* hidden   = (const float*)d_in[0];  // [B, D] f32
    // d_in[1] = target (unused by the reference computation)
    const int*   path     = (const int*)d_in[2];    // [B, P]
    const int*   path_len = (const int*)d_in[3];    // [B]
    const int*   code     = (const int*)d_in[4];    // [B, P]
    const float* embed    = (const float*)d_in[5];  // [V, D] f32
    float*  out      = (float*)d_out;
    float2* partials = (float2*)d_ws;               // 8192 * 8B = 64 KB

    hs_loss_kernel<<<BB / 4, 256, 0, stream>>>(hidden, path, path_len, code,
                                               embed, partials);
    hs_finalize_kernel<<<1, 1024, 0, stream>>>(partials, out);
}

// Round 12
// 105.046 us; speedup vs baseline: 1.0975x; 1.0975x over previous
//
#include <hip/hip_runtime.h>

// Problem constants (match reference): B=8192, P=32, D=128, V=100000
#define BB 8192
#define PP 32
#define DD 128
#define VV 100000

// R9 skeleton + L3 SELF-WARM prologue (single-variable experiment).
//
// Evidence: R7 (MLP), R8 (sorted), R9 (min line-lookups) neutral; R11 (NT,
// cache-bypass) regressed -> caches matter, request-shaping doesn't. The
// table is L3-cold every replay (268MB poison fill evicts it; FETCH=34MB =
// full unique footprint). Random 512B reads from DRAM pay row-activation
// (~30% streaming eff = the observed 1.7 TB/s); from L3 SRAM they don't.
//
// Warm: grid = 2048 blocks = exactly 8/CU co-resident, so every block's
// prologue streams its contiguous 25KB slice (1600 float4) of the embed
// table -> whole 51MB enters L3 at streaming rate in ~8us, concurrent
// across the machine, before the bulk of the random gathers run. warm_sum
// is folded into the output via *0.0f (no fast-math -> not elidable).
__global__ __launch_bounds__(256) void hs_loss_kernel(
    const float* __restrict__ hidden,      // [B, D]
    const int*   __restrict__ path,        // [B, P]
    const int*   __restrict__ path_len,    // [B]
    const int*   __restrict__ code,        // [B, P]
    const float* __restrict__ embed,       // [V, D]
    float2* __restrict__ partials)         // [BB] {loss_sum, len} per row
{
    const int tid = threadIdx.x;
    const int w   = tid >> 6;              // wave in block, 0..3
    const int l   = tid & 63;              // lane
    const int h   = l >> 5;                // half, 0 or 1
    const int hl  = l & 31;                // lane within half
    const int b   = blockIdx.x * 4 + w;    // this wave's batch row

    __shared__ float plds[4][PP * 33];     // 4 wave-private slices, 16.5 KB
    float* const myp = plds[w];

    // ---- warm prologue: stream this block's 1600-float4 table slice ----
    float wsum = 0.0f;
    {
        const float4* wbase = (const float4*)embed;
        const int total4 = (VV * DD) / 4;            // 3.2M float4
        const int s0 = blockIdx.x * 1600;
        #pragma unroll
        for (int k = 0; k < 7; ++k) {
            const int i = s0 + k * 256 + tid;
            if (k * 256 + tid < 1600 && i < total4) {
                const float4 v = wbase[i];
                wsum += v.x;                          // keeps the load live
            }
        }
    }

    const int len   = path_len[b];         // wave-uniform
    const int idx_l = path[b * PP + hl];   // lane hl holds pair hl's index
    const int cd_l  = code[b * PP + hl];   // (both halves duplicate)

    // lane's 16B slice of the hidden row (both halves identical)
    const float4 hv = ((const float4*)(hidden + (size_t)b * DD))[hl];

    // ---- phase 1: batched full-row loads + partial dots (as R9) ----
    #pragma unroll
    for (int batch = 0; batch < 4; ++batch) {
        const int p0 = batch * 8;          // this batch covers pids p0..p0+7
        if (p0 < len) {                    // wave-uniform batch skip
            int pid[4];
            float4 e[4];
            #pragma unroll
            for (int j = 0; j < 4; ++j) {
                pid[j] = p0 + 2 * j + h;   // halves interleave pairs
                const int idx = __shfl(idx_l, pid[j]);
                if (pid[j] < len)          // half-uniform exec mask
                    e[j] = ((const float4*)(embed + (size_t)idx * DD))[hl];
            }
            #pragma unroll
            for (int j = 0; j < 4; ++j) {
                if (pid[j] < len) {
                    const float pr = e[j].x * hv.x + e[j].y * hv.y
                                   + e[j].z * hv.z + e[j].w * hv.w;
                    myp[pid[j] * 33 + hl] = pr;
                }
            }
        }
    }

    // ---- phase 2: half-split partial-sum (same-wave LDS, no barrier) ----
    const int lp = l & 31;                 // pair this lane reduces
    const int kb = h * 16;                 // lanes 0-31: k 0..15; 32-63: 16..31
    float psum = 0.0f;
    #pragma unroll
    for (int k = 0; k < 16; ++k) psum += myp[lp * 33 + kb + k];
    const float dot = psum + __shfl_xor(psum, 32);

    // ---- phase 3: softplus + wave reduction ----
    float loss = 0.0f;
    if (l < 32 && lp < len) {
        // loss = softplus(code ? -dot : dot), stable BCE form
        const float z = cd_l ? -dot : dot;
        loss = fmaxf(z, 0.0f) + __logf(1.0f + __expf(-fabsf(z)));
    }
    #pragma unroll
    for (int m = 1; m <= 32; m <<= 1) loss += __shfl_xor(loss, m);
    if (l == 0)
        partials[b] = make_float2(loss + wsum * 0.0f, (float)len);
}

// Single-block reduction of the 8192 per-row partials + final divide.
__global__ __launch_bounds__(1024) void hs_finalize_kernel(
    const float2* __restrict__ partials, float* __restrict__ out)
{
    const int tid = threadIdx.x;
    float ls = 0.0f, cs = 0.0f;
    #pragma unroll
    for (int k = 0; k < BB / 1024; ++k) {
        const float2 v = partials[tid + k * 1024];
        ls += v.x;
        cs += v.y;
    }
    #pragma unroll
    for (int m = 1; m <= 32; m <<= 1) {
        ls += __shfl_xor(ls, m);
        cs += __shfl_xor(cs, m);
    }
    __shared__ float s_l[16], s_c[16];
    const int wave = tid >> 6;
    if ((tid & 63) == 0) { s_l[wave] = ls; s_c[wave] = cs; }
    __syncthreads();
    if (tid == 0) {
        float L = 0.0f, C = 0.0f;
        #pragma unroll
        for (int wv = 0; wv < 16; ++wv) { L += s_l[wv]; C += s_c[wv]; }
        out[0] = L / C;
    }
}

extern "C" void kernel_launch(void* const* d_in, const int* in_sizes, int n_in,
                              void* d_out, int out_size, void* d_ws, size_t ws_size,
                              hipStream_t stream) {
    const float* hidden   = (const float*)d_in[0];  // [B, D] f32
    // d_in[1] = target (unused by the reference computation)
    const int*   path     = (const int*)d_in[2];    // [B, P]
    const int*   path_len = (const int*)d_in[3];    // [B]
    const int*   code     = (const int*)d_in[4];    // [B, P]
    const float* embed    = (const float*)d_in[5];  // [V, D] f32
    float*  out      = (float*)d_out;
    float2* partials = (float2*)d_ws;               // 8192 * 8B = 64 KB

    hs_loss_kernel<<<BB / 4, 256, 0, stream>>>(hidden, path, path_len, code,
                                               embed, partials);
    hs_finalize_kernel<<<1, 1024, 0, stream>>>(partials, out);
}